// Round 3
// baseline (220.126 us; speedup 1.0000x reference)
//
#include <hip/hip_runtime.h>

// LennardJones segment-sum, round 9 (resubmit — R2 bench died with an
// infra-side "container failed twice"; kernel audit found no hang/fault
// hazard, so the R9 structure and predictions stand).
// R8 post-mortem: occupancy 31->59% bought only 55->50us; VALU 14%, BW 20%
// -> per-wave latency chains, not occupancy. Two suspects: (1) pint[16]+
// meta[16]=32 values live across the scan barrier with VGPR_Count=28 ->
// forced spill/AGPR shuffling; (2) per-element ds_add_rtn (~120cy) chains.
// R9: two-pass bin. Pass 1 is fire-and-forget: compute pint[16] (only 16
// regs live across barriers) + NO-RETURN ds_add histogram. Scan seeds
// rankc[tid]=excl so pass 2 needs exactly one ds_add_rtn per element:
// reload seg (16KB, L2-hot), pos=atomicAdd(&rankc[bucket],1), LDS scatter,
// coalesced write-out. Accum/reduce unchanged (theory: ~10us each).

#define NPB       512            // nodes per bucket (9-bit local id)
#define NPB_MASK  511
#define NB_MAX    256
#define TILE      4096           // pairs per lj_bin block
#define SB        8              // accumulation slices

__device__ __forceinline__ float lj_pair_val(float q, float s6, float s12, float twoeps) {
    const float inv_denom = 1.0f / 262144.0f;   // 1/(100-36)^3, exact pow2
    float inv_r2  = (q > 0.0f) ? (1.0f / q) : 0.0f;
    float inv_r6  = inv_r2 * inv_r2 * inv_r2;
    float inv_r12 = inv_r6 * inv_r6;
    float pair_e  = twoeps * (s12 * inv_r12 - s6 * inv_r6);
    float sw;
    if (q < 36.0f) {
        sw = 1.0f;
    } else if (q < 100.0f) {
        float d = 100.0f - q;
        sw = d * d * (2.0f * q - 8.0f) * inv_denom;
    } else {
        sw = 0.0f;
    }
    return sw * pair_e;
}

// ===== lj_bin: two-pass (histogram, then rank+scatter), deterministic
// per-block region, wave-shfl scan =====
__global__ __launch_bounds__(256) void lj_bin(
    const float* __restrict__ R, const int* __restrict__ seg,
    const float* __restrict__ sigma_p, const float* __restrict__ eps_p,
    int* __restrict__ bins, int* __restrict__ table,
    int n_pairs)
{
    __shared__ int cursor[NB_MAX];                 // per-bucket count
    __shared__ int rankc[NB_MAX];                  // excl-seeded rank counter
    __shared__ int wtot[4];                        // per-wave scan totals
    __shared__ __align__(16) int ldsdata[TILE];    // packed, bucket-grouped

    const int tid = threadIdx.x;
    cursor[tid] = 0;
    __syncthreads();                               // barrier A

    const float sg = sigma_p[0], ep = eps_p[0];
    const float s2 = sg * sg, s6 = s2 * s2 * s2, s12 = s6 * s6;
    const float twoeps = 2.0f * ep;

    const int tile0 = blockIdx.x * TILE;
    int pint[16];   // packed value|local — the ONLY state live across barriers

    // ---- Pass 1: compute packed values, no-return histogram ----
    #pragma unroll
    for (int g = 0; g < 4; ++g) {
        const int base = tile0 + g * 1024 + tid * 4;
        float q[4]; int nd[4]; int okcnt;
        if (base + 4 <= n_pairs) {
            const float4* Rv = (const float4*)(R + (size_t)base * 3);
            float4 a = Rv[0], b4 = Rv[1], c = Rv[2];
            int4 iv = *(const int4*)(seg + base);
            q[0] = a.x*a.x + a.y*a.y + a.z*a.z;
            q[1] = a.w*a.w + b4.x*b4.x + b4.y*b4.y;
            q[2] = b4.z*b4.z + b4.w*b4.w + c.x*c.x;
            q[3] = c.y*c.y + c.z*c.z + c.w*c.w;
            nd[0] = iv.x; nd[1] = iv.y; nd[2] = iv.z; nd[3] = iv.w;
            okcnt = 4;
        } else {
            okcnt = n_pairs - base;
            if (okcnt < 0) okcnt = 0;
            if (okcnt > 4) okcnt = 4;
            for (int k = 0; k < 4; ++k) {
                if (k < okcnt) {
                    int p = base + k;
                    float x = R[(size_t)p*3], y = R[(size_t)p*3+1], z = R[(size_t)p*3+2];
                    q[k] = x*x + y*y + z*z;
                    nd[k] = seg[p];
                } else { q[k] = 0.0f; nd[k] = 0; }
            }
        }
        #pragma unroll
        for (int k = 0; k < 4; ++k) {
            const int e = g * 4 + k;
            float v = lj_pair_val(q[k], s6, s12, twoeps);
            pint[e] = (__float_as_int(v) & ~NPB_MASK) | (nd[k] & NPB_MASK);
            if (k < okcnt)
                atomicAdd(&cursor[nd[k] >> 9], 1);   // result unused -> ds_add (no rtn)
        }
    }

    __syncthreads();                               // barrier B

    // ---- Exclusive scan of the 256 counts: wave-shfl + cross-wave totals ----
    const int wv = tid >> 6, ln = tid & 63;
    const int cnt = cursor[tid];
    int incl = cnt;
    #pragma unroll
    for (int d = 1; d < 64; d <<= 1) {
        int v = __shfl_up(incl, d);
        if (ln >= d) incl += v;
    }
    if (ln == 63) wtot[wv] = incl;
    __syncthreads();                               // barrier C
    int pre = 0;
    #pragma unroll
    for (int w = 0; w < 4; ++w) pre += (w < wv) ? wtot[w] : 0;
    const int excl = pre + incl - cnt;
    rankc[tid] = excl;                             // seed rank counter with excl
    // Prefix row for this block: start-of-bucket | count<<16 (both <= 4096).
    table[(size_t)blockIdx.x * NB_MAX + tid] = excl | (cnt << 16);
    __syncthreads();                               // barrier D

    // ---- Pass 2: reload seg (L2-hot), single rank atomic, LDS scatter ----
    #pragma unroll
    for (int g = 0; g < 4; ++g) {
        const int base = tile0 + g * 1024 + tid * 4;
        int nd[4]; int okcnt;
        if (base + 4 <= n_pairs) {
            int4 iv = *(const int4*)(seg + base);
            nd[0] = iv.x; nd[1] = iv.y; nd[2] = iv.z; nd[3] = iv.w;
            okcnt = 4;
        } else {
            okcnt = n_pairs - base;
            if (okcnt < 0) okcnt = 0;
            if (okcnt > 4) okcnt = 4;
            for (int k = 0; k < 4; ++k) nd[k] = (k < okcnt) ? seg[base + k] : 0;
        }
        #pragma unroll
        for (int k = 0; k < 4; ++k) {
            if (k < okcnt) {
                int pos = atomicAdd(&rankc[nd[k] >> 9], 1);
                ldsdata[pos] = pint[g * 4 + k];
            }
        }
    }
    __syncthreads();                               // barrier E

    // Unconditional contiguous write of the whole region (int4, perfectly
    // coalesced). Slots beyond the filled total are garbage but never read:
    // accum touches only [excl, excl+cnt) per bucket.
    int* dst = bins + (size_t)blockIdx.x * TILE;
    #pragma unroll
    for (int g = 0; g < 4; ++g) {
        const int idx = g * 1024 + tid * 4;
        *(int4*)(dst + idx) = *(const int4*)(ldsdata + idx);
    }
}

// ===== lj_accum: one block per (bucket, slice); gather its bucket's
// segment from every slice-assigned bin-block region (L2/L3-resident) =====
__global__ __launch_bounds__(256) void lj_accum(
    const int* __restrict__ bins, const int* __restrict__ table,
    float* __restrict__ partials, int nb, int nblocks)
{
    const int b = blockIdx.x % nb;
    const int s = blockIdx.x / nb;      // slice index

    __shared__ float acc[NPB];
    for (int l = threadIdx.x; l < NPB; l += 256) acc[l] = 0.0f;
    __syncthreads();

    // Thread t handles regions rblk = s + SB*(t + 256*iter).
    for (int rblk = s + SB * (int)threadIdx.x; rblk < nblocks; rblk += SB * 256) {
        const int pe  = table[(size_t)rblk * NB_MAX + b];
        const int cnt = pe >> 16;
        const int* p  = bins + (size_t)rblk * TILE + (pe & 0xFFFF);
        int k = 0;
        for (; k + 3 < cnt; k += 4) {          // 4-way unroll for MLP
            int e0 = p[k], e1 = p[k+1], e2 = p[k+2], e3 = p[k+3];
            atomicAdd(&acc[e0 & NPB_MASK], __int_as_float(e0 & ~NPB_MASK));
            atomicAdd(&acc[e1 & NPB_MASK], __int_as_float(e1 & ~NPB_MASK));
            atomicAdd(&acc[e2 & NPB_MASK], __int_as_float(e2 & ~NPB_MASK));
            atomicAdd(&acc[e3 & NPB_MASK], __int_as_float(e3 & ~NPB_MASK));
        }
        for (; k < cnt; ++k) {
            int e = p[k];
            atomicAdd(&acc[e & NPB_MASK], __int_as_float(e & ~NPB_MASK));
        }
    }
    __syncthreads();

    float* dst = partials + (size_t)s * ((size_t)nb * NPB) + (size_t)b * NPB;
    for (int l = threadIdx.x; l < NPB; l += 256) dst[l] = acc[l];
}

// ===== lj_reduce: 4 nodes/thread, float4 =====
__global__ __launch_bounds__(256) void lj_reduce(
    const float* __restrict__ partials, float* __restrict__ out, int n_nodes, int nb)
{
    const size_t stride = (size_t)nb * NPB;
    const int n = (blockIdx.x * blockDim.x + threadIdx.x) * 4;
    if (n + 3 < n_nodes) {
        float4 sum = make_float4(0.f, 0.f, 0.f, 0.f);
        #pragma unroll
        for (int s = 0; s < SB; ++s) {
            const float4 p = *(const float4*)(partials + (size_t)s * stride + n);
            sum.x += p.x; sum.y += p.y; sum.z += p.z; sum.w += p.w;
        }
        *(float4*)(out + n) = sum;
    } else {
        for (int m = n; m < n_nodes; ++m) {
            float sum = 0.f;
            #pragma unroll
            for (int s = 0; s < SB; ++s)
                sum += partials[(size_t)s * stride + m];
            out[m] = sum;
        }
    }
}

// Fallback: direct device-scope atomics (round-1 kernel).
__global__ __launch_bounds__(256) void lj_pair_scatter(
    const float* __restrict__ R, const int* __restrict__ seg,
    const float* __restrict__ sigma_p, const float* __restrict__ eps_p,
    float* __restrict__ out, int n_pairs)
{
    const float sg = sigma_p[0], ep = eps_p[0];
    const float s2 = sg*sg, s6 = s2*s2*s2, s12 = s6*s6;
    const float twoeps = 2.0f * ep;
    const int t = blockIdx.x * blockDim.x + threadIdx.x;
    const int nthreads = gridDim.x * blockDim.x;
    for (int base = t * 4; base < n_pairs; base += nthreads * 4) {
        if (base + 3 < n_pairs) {
            const float4* Rv = (const float4*)(R + (size_t)base * 3);
            float4 a = Rv[0], b = Rv[1], c = Rv[2];
            int4 iv = *(const int4*)(seg + base);
            float r2[4];
            r2[0] = a.x*a.x + a.y*a.y + a.z*a.z;
            r2[1] = a.w*a.w + b.x*b.x + b.y*b.y;
            r2[2] = b.z*b.z + b.w*b.w + c.x*c.x;
            r2[3] = c.y*c.y + c.z*c.z + c.w*c.w;
            const int ii[4] = {iv.x, iv.y, iv.z, iv.w};
            #pragma unroll
            for (int k = 0; k < 4; ++k)
                atomicAdd(&out[ii[k]], lj_pair_val(r2[k], s6, s12, twoeps));
        } else {
            for (int p = base; p < n_pairs; ++p) {
                float x = R[(size_t)p*3], y = R[(size_t)p*3+1], z = R[(size_t)p*3+2];
                atomicAdd(&out[seg[p]], lj_pair_val(x*x+y*y+z*z, s6, s12, twoeps));
            }
        }
    }
}

extern "C" void kernel_launch(void* const* d_in, const int* in_sizes, int n_in,
                              void* d_out, int out_size, void* d_ws, size_t ws_size,
                              hipStream_t stream) {
    // Inputs: 0 R_ij f32[n_pairs,3], 1 i i32[n_pairs], 2 j (unused),
    // 3 Z_i (shape only), 4 pair_mask (all True), 5 node_mask (all True),
    // 6 sigma f32[1], 7 epsilon f32[1]
    const float* R     = (const float*)d_in[0];
    const int*   seg   = (const int*)d_in[1];
    const float* sigma = (const float*)d_in[6];
    const float* eps   = (const float*)d_in[7];
    float* out = (float*)d_out;

    const int n_pairs = in_sizes[1];
    const int n_nodes = out_size;
    const int nb = (n_nodes + NPB - 1) / NPB;
    const int nblocks = (n_pairs + TILE - 1) / TILE;

    const size_t bin_bytes  = (size_t)nblocks * TILE * sizeof(int);
    const size_t tab_bytes  = (size_t)nblocks * NB_MAX * sizeof(int);
    const size_t part_bytes = (size_t)SB * nb * NPB * sizeof(float);
    const size_t need = bin_bytes + tab_bytes + part_bytes;

    if (nb >= 1 && nb <= NB_MAX && nblocks >= 1 && ws_size >= need) {
        int*   bins     = (int*)d_ws;
        int*   table    = (int*)((char*)d_ws + bin_bytes);
        float* partials = (float*)((char*)d_ws + bin_bytes + tab_bytes);

        lj_bin<<<nblocks, 256, 0, stream>>>(R, seg, sigma, eps, bins, table, n_pairs);
        lj_accum<<<nb * SB, 256, 0, stream>>>(bins, table, partials, nb, nblocks);
        lj_reduce<<<(n_nodes + 1023) / 1024, 256, 0, stream>>>(partials, out, n_nodes, nb);
    } else {
        hipMemsetAsync(d_out, 0, (size_t)out_size * sizeof(float), stream);
        const int grid = (n_pairs + 1023) / 1024;
        lj_pair_scatter<<<grid, 256, 0, stream>>>(R, seg, sigma, eps, out, n_pairs);
    }
}

// Round 4
// 219.084 us; speedup vs baseline: 1.0048x; 1.0048x over previous
//
#include <hip/hip_runtime.h>

// LennardJones segment-sum, round 10.
// R7/R8/R9 all land at 50-55us for lj_bin with no pipe >25% busy ->
// latency-stall bound. VGPR=36 proves pass-1 ran as 4 serialized rounds of
// {4 loads, vmcnt(0), compute}. R10: (1) hoist all 16 loads per thread
// (fast path for full tiles), accepting ~85 VGPR; (2) stash bucket bytes
// in 4KB LDS so pass 2 does zero global loads (-12MB FETCH); (3) accum
// rewritten wave-cooperative (preload excl|cnt table to LDS, one coalesced
// gather + LDS atomic per region) instead of 21 dependent scalar loads per
// thread; (4) reduce folded into accum via coalesced global atomics on a
// memset-zeroed out (-1 dispatch, -6.4MB partials traffic).

#define NPB       512            // nodes per bucket (9-bit local id)
#define NPB_MASK  511
#define NB_MAX    256
#define TILE      4096           // pairs per lj_bin block
#define SB        8              // accumulation slices

__device__ __forceinline__ float lj_pair_val(float q, float s6, float s12, float twoeps) {
    const float inv_denom = 1.0f / 262144.0f;   // 1/(100-36)^3, exact pow2
    float inv_r2  = (q > 0.0f) ? (1.0f / q) : 0.0f;
    float inv_r6  = inv_r2 * inv_r2 * inv_r2;
    float inv_r12 = inv_r6 * inv_r6;
    float pair_e  = twoeps * (s12 * inv_r12 - s6 * inv_r6);
    float sw;
    if (q < 36.0f) {
        sw = 1.0f;
    } else if (q < 100.0f) {
        float d = 100.0f - q;
        sw = d * d * (2.0f * q - 8.0f) * inv_denom;
    } else {
        sw = 0.0f;
    }
    return sw * pair_e;
}

// ===== lj_bin: 16-deep hoisted loads, LDS bucket stash, two-pass rank =====
__global__ __launch_bounds__(256) void lj_bin(
    const float* __restrict__ R, const int* __restrict__ seg,
    const float* __restrict__ sigma_p, const float* __restrict__ eps_p,
    int* __restrict__ bins, int* __restrict__ table,
    int n_pairs)
{
    __shared__ int cursor[NB_MAX];                 // per-bucket count
    __shared__ int rankc[NB_MAX];                  // excl-seeded rank counter
    __shared__ int wtot[4];                        // per-wave scan totals
    __shared__ int buckpk[TILE / 4];               // 4KB: 4 bucket bytes/word
    __shared__ __align__(16) int ldsdata[TILE];    // packed, bucket-grouped

    const int tid = threadIdx.x;
    cursor[tid] = 0;
    __syncthreads();                               // barrier A

    const float sg = sigma_p[0], ep = eps_p[0];
    const float s2 = sg * sg, s6 = s2 * s2 * s2, s12 = s6 * s6;
    const float twoeps = 2.0f * ep;

    const int tile0  = blockIdx.x * TILE;
    const int nvalid = min(TILE, n_pairs - tile0);
    int pint[16];   // packed value|local

    if (nvalid == TILE) {
        // ---- Fast path (all but the last block): hoist ALL 16 loads ----
        float4 A[4], B[4], C[4]; int4 I[4];
        #pragma unroll
        for (int g = 0; g < 4; ++g) {
            const int base = tile0 + g * 1024 + tid * 4;
            const float4* Rv = (const float4*)(R + (size_t)base * 3);
            A[g] = Rv[0]; B[g] = Rv[1]; C[g] = Rv[2];
            I[g] = *(const int4*)(seg + base);
        }
        #pragma unroll
        for (int g = 0; g < 4; ++g) {
            const int n0 = I[g].x, n1 = I[g].y, n2 = I[g].z, n3 = I[g].w;
            const int b0 = n0 >> 9, b1 = n1 >> 9, b2 = n2 >> 9, b3 = n3 >> 9;
            // Histogram + stash first: depends only on I[g], hides DS latency
            // under the LJ VALU chain below.
            atomicAdd(&cursor[b0], 1);
            atomicAdd(&cursor[b1], 1);
            atomicAdd(&cursor[b2], 1);
            atomicAdd(&cursor[b3], 1);
            buckpk[g * 256 + tid] = b0 | (b1 << 8) | (b2 << 16) | (b3 << 24);
            float q0 = A[g].x*A[g].x + A[g].y*A[g].y + A[g].z*A[g].z;
            float q1 = A[g].w*A[g].w + B[g].x*B[g].x + B[g].y*B[g].y;
            float q2 = B[g].z*B[g].z + B[g].w*B[g].w + C[g].x*C[g].x;
            float q3 = C[g].y*C[g].y + C[g].z*C[g].z + C[g].w*C[g].w;
            pint[g*4+0] = (__float_as_int(lj_pair_val(q0, s6, s12, twoeps)) & ~NPB_MASK) | (n0 & NPB_MASK);
            pint[g*4+1] = (__float_as_int(lj_pair_val(q1, s6, s12, twoeps)) & ~NPB_MASK) | (n1 & NPB_MASK);
            pint[g*4+2] = (__float_as_int(lj_pair_val(q2, s6, s12, twoeps)) & ~NPB_MASK) | (n2 & NPB_MASK);
            pint[g*4+3] = (__float_as_int(lj_pair_val(q3, s6, s12, twoeps)) & ~NPB_MASK) | (n3 & NPB_MASK);
        }
    } else {
        // ---- Tail path (last block only): scalar, guarded ----
        #pragma unroll
        for (int g = 0; g < 4; ++g) {
            int pk = 0;
            #pragma unroll
            for (int k = 0; k < 4; ++k) {
                const int li = g * 1024 + tid * 4 + k;
                int nd = 0; float q = 0.0f;
                if (li < nvalid) {
                    const int p = tile0 + li;
                    float x = R[(size_t)p*3], y = R[(size_t)p*3+1], z = R[(size_t)p*3+2];
                    q = x*x + y*y + z*z;
                    nd = seg[p];
                    atomicAdd(&cursor[nd >> 9], 1);
                }
                pk |= (nd >> 9) << (8 * k);
                pint[g*4+k] = (__float_as_int(lj_pair_val(q, s6, s12, twoeps)) & ~NPB_MASK) | (nd & NPB_MASK);
            }
            buckpk[g * 256 + tid] = pk;
        }
    }

    __syncthreads();                               // barrier B

    // ---- Exclusive scan of the 256 counts: wave-shfl + cross-wave totals ----
    const int wv = tid >> 6, ln = tid & 63;
    const int cnt = cursor[tid];
    int incl = cnt;
    #pragma unroll
    for (int d = 1; d < 64; d <<= 1) {
        int v = __shfl_up(incl, d);
        if (ln >= d) incl += v;
    }
    if (ln == 63) wtot[wv] = incl;
    __syncthreads();                               // barrier C
    int pre = 0;
    #pragma unroll
    for (int w = 0; w < 4; ++w) pre += (w < wv) ? wtot[w] : 0;
    const int excl = pre + incl - cnt;
    rankc[tid] = excl;                             // seed rank counter with excl
    // Prefix row for this block: start-of-bucket | count<<16 (both <= 4096).
    table[(size_t)blockIdx.x * NB_MAX + tid] = excl | (cnt << 16);
    __syncthreads();                               // barrier D

    // ---- Pass 2: buckets from LDS stash, single rank atomic, LDS scatter ----
    #pragma unroll
    for (int g = 0; g < 4; ++g) {
        const int pk = buckpk[g * 256 + tid];
        #pragma unroll
        for (int k = 0; k < 4; ++k) {
            const int li = g * 1024 + tid * 4 + k;
            if (li < nvalid) {
                const int b = (pk >> (8 * k)) & 255;
                const int pos = atomicAdd(&rankc[b], 1);
                ldsdata[pos] = pint[g * 4 + k];
            }
        }
    }
    __syncthreads();                               // barrier E

    // Unconditional contiguous int4 write of the whole region. Slots beyond
    // the fill point are garbage but never read (accum walks [excl,excl+cnt)).
    int* dst = bins + (size_t)blockIdx.x * TILE;
    #pragma unroll
    for (int g = 0; g < 4; ++g) {
        const int idx = g * 1024 + tid * 4;
        *(int4*)(dst + idx) = *(const int4*)(ldsdata + idx);
    }
}

// ===== lj_accum: one block per (bucket, slice); wave-cooperative gather of
// this bucket's segment from every slice-assigned region; adds into out =====
__global__ __launch_bounds__(256) void lj_accum(
    const int* __restrict__ bins, const int* __restrict__ table,
    float* __restrict__ out, int nb, int nblocks, int n_nodes)
{
    const int b = blockIdx.x % nb;
    const int s = blockIdx.x / nb;      // slice index
    const int tid = threadIdx.x;
    const int wv = tid >> 6, ln = tid & 63;

    __shared__ float acc[NPB];
    __shared__ int pe_lds[256];
    for (int l = tid; l < NPB; l += 256) acc[l] = 0.0f;

    // Regions for this (b,s): rblk = s + SB*r, r = 0..nreg-1.
    const int nreg = (nblocks - s + SB - 1) / SB;

    for (int chunk = 0; chunk < nreg; chunk += 256) {
        const int nthis = min(256, nreg - chunk);
        __syncthreads();
        if (tid < nthis)
            pe_lds[tid] = table[(size_t)(s + SB * (chunk + tid)) * NB_MAX + b];
        __syncthreads();
        // Each wave processes whole regions: one coalesced load + one LDS
        // atomic per element, lanes 0..cnt-1 active.
        for (int r = wv; r < nthis; r += 4) {
            const int pe  = pe_lds[r];
            const int cnt = pe >> 16;
            const int* p  = bins + (size_t)(s + SB * (chunk + r)) * TILE + (pe & 0xFFFF);
            for (int k = ln; k < cnt; k += 64) {
                const int e = p[k];
                atomicAdd(&acc[e & NPB_MASK], __int_as_float(e & ~NPB_MASK));
            }
        }
    }
    __syncthreads();

    const int node0 = b * NPB;
    for (int l = tid; l < NPB; l += 256) {
        const int node = node0 + l;
        if (node < n_nodes) {
            const float v = acc[l];
            if (v != 0.0f) atomicAdd(&out[node], v);
        }
    }
}

// Fallback: direct device-scope atomics (round-1 kernel).
__global__ __launch_bounds__(256) void lj_pair_scatter(
    const float* __restrict__ R, const int* __restrict__ seg,
    const float* __restrict__ sigma_p, const float* __restrict__ eps_p,
    float* __restrict__ out, int n_pairs)
{
    const float sg = sigma_p[0], ep = eps_p[0];
    const float s2 = sg*sg, s6 = s2*s2*s2, s12 = s6*s6;
    const float twoeps = 2.0f * ep;
    const int t = blockIdx.x * blockDim.x + threadIdx.x;
    const int nthreads = gridDim.x * blockDim.x;
    for (int base = t * 4; base < n_pairs; base += nthreads * 4) {
        if (base + 3 < n_pairs) {
            const float4* Rv = (const float4*)(R + (size_t)base * 3);
            float4 a = Rv[0], b = Rv[1], c = Rv[2];
            int4 iv = *(const int4*)(seg + base);
            float r2[4];
            r2[0] = a.x*a.x + a.y*a.y + a.z*a.z;
            r2[1] = a.w*a.w + b.x*b.x + b.y*b.y;
            r2[2] = b.z*b.z + b.w*b.w + c.x*c.x;
            r2[3] = c.y*c.y + c.z*c.z + c.w*c.w;
            const int ii[4] = {iv.x, iv.y, iv.z, iv.w};
            #pragma unroll
            for (int k = 0; k < 4; ++k)
                atomicAdd(&out[ii[k]], lj_pair_val(r2[k], s6, s12, twoeps));
        } else {
            for (int p = base; p < n_pairs; ++p) {
                float x = R[(size_t)p*3], y = R[(size_t)p*3+1], z = R[(size_t)p*3+2];
                atomicAdd(&out[seg[p]], lj_pair_val(x*x+y*y+z*z, s6, s12, twoeps));
            }
        }
    }
}

extern "C" void kernel_launch(void* const* d_in, const int* in_sizes, int n_in,
                              void* d_out, int out_size, void* d_ws, size_t ws_size,
                              hipStream_t stream) {
    // Inputs: 0 R_ij f32[n_pairs,3], 1 i i32[n_pairs], 2 j (unused),
    // 3 Z_i (shape only), 4 pair_mask (all True), 5 node_mask (all True),
    // 6 sigma f32[1], 7 epsilon f32[1]
    const float* R     = (const float*)d_in[0];
    const int*   seg   = (const int*)d_in[1];
    const float* sigma = (const float*)d_in[6];
    const float* eps   = (const float*)d_in[7];
    float* out = (float*)d_out;

    const int n_pairs = in_sizes[1];
    const int n_nodes = out_size;
    const int nb = (n_nodes + NPB - 1) / NPB;
    const int nblocks = (n_pairs + TILE - 1) / TILE;

    const size_t bin_bytes = (size_t)nblocks * TILE * sizeof(int);
    const size_t tab_bytes = (size_t)nblocks * NB_MAX * sizeof(int);
    const size_t need = bin_bytes + tab_bytes;

    if (nb >= 1 && nb <= NB_MAX && nblocks >= 1 && ws_size >= need) {
        int* bins  = (int*)d_ws;
        int* table = (int*)((char*)d_ws + bin_bytes);

        hipMemsetAsync(d_out, 0, (size_t)n_nodes * sizeof(float), stream);
        lj_bin<<<nblocks, 256, 0, stream>>>(R, seg, sigma, eps, bins, table, n_pairs);
        lj_accum<<<nb * SB, 256, 0, stream>>>(bins, table, out, nb, nblocks, n_nodes);
    } else {
        hipMemsetAsync(d_out, 0, (size_t)out_size * sizeof(float), stream);
        const int grid = (n_pairs + 1023) / 1024;
        lj_pair_scatter<<<grid, 256, 0, stream>>>(R, seg, sigma, eps, out, n_pairs);
    }
}

// Round 5
// 212.146 us; speedup vs baseline: 1.0376x; 1.0327x over previous
//
#include <hip/hip_runtime.h>

// LennardJones segment-sum, round 11.
// R10 post-mortem: accum (50us) now tops the profile; bin dropped below
// 50 (absent from top-5) -> the load-hoist fixed bin, but the wave-coop
// accum rewrite was a REGRESSION: MLP fell from ~195 region-streams/block
// (R8 per-thread) to 4 (per-wave serial region loop) -> ~4KB in flight/CU
// vs ~17KB needed at 700ns latency -> measured 0.72 TB/s. R11: revert
// accum to per-thread regions (scalar loads, 4-way unroll) keeping the
// direct-to-out fold; fold the out-zeroing into bin (-1 dispatch); bin
// frozen at R10 so both kernel durations become visible next round.

#define NPB       512            // nodes per bucket (9-bit local id)
#define NPB_MASK  511
#define NB_MAX    256
#define TILE      4096           // pairs per lj_bin block
#define SB        8              // accumulation slices

__device__ __forceinline__ float lj_pair_val(float q, float s6, float s12, float twoeps) {
    const float inv_denom = 1.0f / 262144.0f;   // 1/(100-36)^3, exact pow2
    float inv_r2  = (q > 0.0f) ? (1.0f / q) : 0.0f;
    float inv_r6  = inv_r2 * inv_r2 * inv_r2;
    float inv_r12 = inv_r6 * inv_r6;
    float pair_e  = twoeps * (s12 * inv_r12 - s6 * inv_r6);
    float sw;
    if (q < 36.0f) {
        sw = 1.0f;
    } else if (q < 100.0f) {
        float d = 100.0f - q;
        sw = d * d * (2.0f * q - 8.0f) * inv_denom;
    } else {
        sw = 0.0f;
    }
    return sw * pair_e;
}

// ===== lj_bin: 16-deep hoisted loads, LDS bucket stash, two-pass rank
// (R10 structure, frozen) + out-zeroing preamble =====
__global__ __launch_bounds__(256) void lj_bin(
    const float* __restrict__ R, const int* __restrict__ seg,
    const float* __restrict__ sigma_p, const float* __restrict__ eps_p,
    int* __restrict__ bins, int* __restrict__ table,
    float* __restrict__ out, int n_pairs, int n_nodes)
{
    __shared__ int cursor[NB_MAX];                 // per-bucket count
    __shared__ int rankc[NB_MAX];                  // excl-seeded rank counter
    __shared__ int wtot[4];                        // per-wave scan totals
    __shared__ int buckpk[TILE / 4];               // 4KB: 4 bucket bytes/word
    __shared__ __align__(16) int ldsdata[TILE];    // packed, bucket-grouped

    const int tid = threadIdx.x;
    cursor[tid] = 0;

    // Zero this block's 64-float chunk of out (replaces the memset dispatch;
    // host guarantees nblocks*64 >= n_nodes on this path). Independent of
    // everything below; accum runs in a later dispatch.
    {
        const int n = blockIdx.x * 64 + tid;
        if (tid < 64 && n < n_nodes) out[n] = 0.0f;
    }
    __syncthreads();                               // barrier A

    const float sg = sigma_p[0], ep = eps_p[0];
    const float s2 = sg * sg, s6 = s2 * s2 * s2, s12 = s6 * s6;
    const float twoeps = 2.0f * ep;

    const int tile0  = blockIdx.x * TILE;
    const int nvalid = min(TILE, n_pairs - tile0);
    int pint[16];   // packed value|local

    if (nvalid == TILE) {
        // ---- Fast path (all but the last block): hoist ALL 16 loads ----
        float4 A[4], B[4], C[4]; int4 I[4];
        #pragma unroll
        for (int g = 0; g < 4; ++g) {
            const int base = tile0 + g * 1024 + tid * 4;
            const float4* Rv = (const float4*)(R + (size_t)base * 3);
            A[g] = Rv[0]; B[g] = Rv[1]; C[g] = Rv[2];
            I[g] = *(const int4*)(seg + base);
        }
        #pragma unroll
        for (int g = 0; g < 4; ++g) {
            const int n0 = I[g].x, n1 = I[g].y, n2 = I[g].z, n3 = I[g].w;
            const int b0 = n0 >> 9, b1 = n1 >> 9, b2 = n2 >> 9, b3 = n3 >> 9;
            // Histogram + stash first: depends only on I[g], hides DS latency
            // under the LJ VALU chain below.
            atomicAdd(&cursor[b0], 1);
            atomicAdd(&cursor[b1], 1);
            atomicAdd(&cursor[b2], 1);
            atomicAdd(&cursor[b3], 1);
            buckpk[g * 256 + tid] = b0 | (b1 << 8) | (b2 << 16) | (b3 << 24);
            float q0 = A[g].x*A[g].x + A[g].y*A[g].y + A[g].z*A[g].z;
            float q1 = A[g].w*A[g].w + B[g].x*B[g].x + B[g].y*B[g].y;
            float q2 = B[g].z*B[g].z + B[g].w*B[g].w + C[g].x*C[g].x;
            float q3 = C[g].y*C[g].y + C[g].z*C[g].z + C[g].w*C[g].w;
            pint[g*4+0] = (__float_as_int(lj_pair_val(q0, s6, s12, twoeps)) & ~NPB_MASK) | (n0 & NPB_MASK);
            pint[g*4+1] = (__float_as_int(lj_pair_val(q1, s6, s12, twoeps)) & ~NPB_MASK) | (n1 & NPB_MASK);
            pint[g*4+2] = (__float_as_int(lj_pair_val(q2, s6, s12, twoeps)) & ~NPB_MASK) | (n2 & NPB_MASK);
            pint[g*4+3] = (__float_as_int(lj_pair_val(q3, s6, s12, twoeps)) & ~NPB_MASK) | (n3 & NPB_MASK);
        }
    } else {
        // ---- Tail path (last block only): scalar, guarded ----
        #pragma unroll
        for (int g = 0; g < 4; ++g) {
            int pk = 0;
            #pragma unroll
            for (int k = 0; k < 4; ++k) {
                const int li = g * 1024 + tid * 4 + k;
                int nd = 0; float q = 0.0f;
                if (li < nvalid) {
                    const int p = tile0 + li;
                    float x = R[(size_t)p*3], y = R[(size_t)p*3+1], z = R[(size_t)p*3+2];
                    q = x*x + y*y + z*z;
                    nd = seg[p];
                    atomicAdd(&cursor[nd >> 9], 1);
                }
                pk |= (nd >> 9) << (8 * k);
                pint[g*4+k] = (__float_as_int(lj_pair_val(q, s6, s12, twoeps)) & ~NPB_MASK) | (nd & NPB_MASK);
            }
            buckpk[g * 256 + tid] = pk;
        }
    }

    __syncthreads();                               // barrier B

    // ---- Exclusive scan of the 256 counts: wave-shfl + cross-wave totals ----
    const int wv = tid >> 6, ln = tid & 63;
    const int cnt = cursor[tid];
    int incl = cnt;
    #pragma unroll
    for (int d = 1; d < 64; d <<= 1) {
        int v = __shfl_up(incl, d);
        if (ln >= d) incl += v;
    }
    if (ln == 63) wtot[wv] = incl;
    __syncthreads();                               // barrier C
    int pre = 0;
    #pragma unroll
    for (int w = 0; w < 4; ++w) pre += (w < wv) ? wtot[w] : 0;
    const int excl = pre + incl - cnt;
    rankc[tid] = excl;                             // seed rank counter with excl
    // Prefix row for this block: start-of-bucket | count<<16 (both <= 4096).
    table[(size_t)blockIdx.x * NB_MAX + tid] = excl | (cnt << 16);
    __syncthreads();                               // barrier D

    // ---- Pass 2: buckets from LDS stash, single rank atomic, LDS scatter ----
    #pragma unroll
    for (int g = 0; g < 4; ++g) {
        const int pk = buckpk[g * 256 + tid];
        #pragma unroll
        for (int k = 0; k < 4; ++k) {
            const int li = g * 1024 + tid * 4 + k;
            if (li < nvalid) {
                const int b = (pk >> (8 * k)) & 255;
                const int pos = atomicAdd(&rankc[b], 1);
                ldsdata[pos] = pint[g * 4 + k];
            }
        }
    }
    __syncthreads();                               // barrier E

    // Unconditional contiguous int4 write of the whole region. Slots beyond
    // the fill point are garbage but never read (accum walks [excl,excl+cnt)).
    int* dst = bins + (size_t)blockIdx.x * TILE;
    #pragma unroll
    for (int g = 0; g < 4; ++g) {
        const int idx = g * 1024 + tid * 4;
        *(int4*)(dst + idx) = *(const int4*)(ldsdata + idx);
    }
}

// ===== lj_accum: one block per (bucket, slice); PER-THREAD regions
// (R8 structure: ~195 concurrent region-streams/block for MLP), adds
// straight into out =====
__global__ __launch_bounds__(256) void lj_accum(
    const int* __restrict__ bins, const int* __restrict__ table,
    float* __restrict__ out, int nb, int nblocks, int n_nodes)
{
    const int b = blockIdx.x % nb;
    const int s = blockIdx.x / nb;      // slice index
    const int tid = threadIdx.x;

    __shared__ float acc[NPB];
    for (int l = tid; l < NPB; l += 256) acc[l] = 0.0f;
    __syncthreads();

    // Thread t handles regions rblk = s + SB*(t + 256*iter): independent
    // scalar-load streams, 4-way unrolled -> high memory-level parallelism.
    for (int rblk = s + SB * tid; rblk < nblocks; rblk += SB * 256) {
        const int pe  = table[(size_t)rblk * NB_MAX + b];
        const int cnt = pe >> 16;
        const int* p  = bins + (size_t)rblk * TILE + (pe & 0xFFFF);
        int k = 0;
        for (; k + 3 < cnt; k += 4) {
            const int e0 = p[k], e1 = p[k+1], e2 = p[k+2], e3 = p[k+3];
            atomicAdd(&acc[e0 & NPB_MASK], __int_as_float(e0 & ~NPB_MASK));
            atomicAdd(&acc[e1 & NPB_MASK], __int_as_float(e1 & ~NPB_MASK));
            atomicAdd(&acc[e2 & NPB_MASK], __int_as_float(e2 & ~NPB_MASK));
            atomicAdd(&acc[e3 & NPB_MASK], __int_as_float(e3 & ~NPB_MASK));
        }
        for (; k < cnt; ++k) {
            const int e = p[k];
            atomicAdd(&acc[e & NPB_MASK], __int_as_float(e & ~NPB_MASK));
        }
    }
    __syncthreads();

    const int node0 = b * NPB;
    for (int l = tid; l < NPB; l += 256) {
        const int node = node0 + l;
        if (node < n_nodes) {
            const float v = acc[l];
            if (v != 0.0f) atomicAdd(&out[node], v);
        }
    }
}

// Fallback: direct device-scope atomics (round-1 kernel).
__global__ __launch_bounds__(256) void lj_pair_scatter(
    const float* __restrict__ R, const int* __restrict__ seg,
    const float* __restrict__ sigma_p, const float* __restrict__ eps_p,
    float* __restrict__ out, int n_pairs)
{
    const float sg = sigma_p[0], ep = eps_p[0];
    const float s2 = sg*sg, s6 = s2*s2*s2, s12 = s6*s6;
    const float twoeps = 2.0f * ep;
    const int t = blockIdx.x * blockDim.x + threadIdx.x;
    const int nthreads = gridDim.x * blockDim.x;
    for (int base = t * 4; base < n_pairs; base += nthreads * 4) {
        if (base + 3 < n_pairs) {
            const float4* Rv = (const float4*)(R + (size_t)base * 3);
            float4 a = Rv[0], b = Rv[1], c = Rv[2];
            int4 iv = *(const int4*)(seg + base);
            float r2[4];
            r2[0] = a.x*a.x + a.y*a.y + a.z*a.z;
            r2[1] = a.w*a.w + b.x*b.x + b.y*b.y;
            r2[2] = b.z*b.z + b.w*b.w + c.x*c.x;
            r2[3] = c.y*c.y + c.z*c.z + c.w*c.w;
            const int ii[4] = {iv.x, iv.y, iv.z, iv.w};
            #pragma unroll
            for (int k = 0; k < 4; ++k)
                atomicAdd(&out[ii[k]], lj_pair_val(r2[k], s6, s12, twoeps));
        } else {
            for (int p = base; p < n_pairs; ++p) {
                float x = R[(size_t)p*3], y = R[(size_t)p*3+1], z = R[(size_t)p*3+2];
                atomicAdd(&out[seg[p]], lj_pair_val(x*x+y*y+z*z, s6, s12, twoeps));
            }
        }
    }
}

extern "C" void kernel_launch(void* const* d_in, const int* in_sizes, int n_in,
                              void* d_out, int out_size, void* d_ws, size_t ws_size,
                              hipStream_t stream) {
    // Inputs: 0 R_ij f32[n_pairs,3], 1 i i32[n_pairs], 2 j (unused),
    // 3 Z_i (shape only), 4 pair_mask (all True), 5 node_mask (all True),
    // 6 sigma f32[1], 7 epsilon f32[1]
    const float* R     = (const float*)d_in[0];
    const int*   seg   = (const int*)d_in[1];
    const float* sigma = (const float*)d_in[6];
    const float* eps   = (const float*)d_in[7];
    float* out = (float*)d_out;

    const int n_pairs = in_sizes[1];
    const int n_nodes = out_size;
    const int nb = (n_nodes + NPB - 1) / NPB;
    const int nblocks = (n_pairs + TILE - 1) / TILE;

    const size_t bin_bytes = (size_t)nblocks * TILE * sizeof(int);
    const size_t tab_bytes = (size_t)nblocks * NB_MAX * sizeof(int);
    const size_t need = bin_bytes + tab_bytes;

    if (nb >= 1 && nb <= NB_MAX && nblocks >= 1 && ws_size >= need) {
        int* bins  = (int*)d_ws;
        int* table = (int*)((char*)d_ws + bin_bytes);

        // bin zeroes out's chunks itself when coverage suffices (one fewer
        // dispatch); otherwise fall back to an explicit memset.
        if ((size_t)nblocks * 64 < (size_t)n_nodes)
            hipMemsetAsync(out, 0, (size_t)n_nodes * sizeof(float), stream);

        lj_bin<<<nblocks, 256, 0, stream>>>(R, seg, sigma, eps, bins, table,
                                            out, n_pairs, n_nodes);
        lj_accum<<<nb * SB, 256, 0, stream>>>(bins, table, out, nb, nblocks, n_nodes);
    } else {
        hipMemsetAsync(d_out, 0, (size_t)out_size * sizeof(float), stream);
        const int grid = (n_pairs + 1023) / 1024;
        lj_pair_scatter<<<grid, 256, 0, stream>>>(R, seg, sigma, eps, out, n_pairs);
    }
}

// Round 6
// 208.046 us; speedup vs baseline: 1.0581x; 1.0197x over previous
//
#include <hip/hip_runtime.h>

// LennardJones segment-sum, round 12.
// R11 post-mortem: (1) a 45us fillBufferAligned (300MB = whole workspace
// re-poison, 6.76 TB/s) sits inside the timed region -> fixed harness cost
// ~110-150us; controllable time is bin 46 + accum ~5-10. (2) VGPR=40 (not
// the predicted ~85) proves the compiler re-sank R10's hoisted loads into
// 4 serialized {4-load, vmcnt, compute} rounds -> ~768B in flight/CU vs
// ~12KB needed. R12: stage R+seg via __builtin_amdgcn_global_load_lds
// width=16 (zero VGPR cost, 32 insts/block fire-and-forget, one wait),
// TILE=2048/256thr, ldsdata aliases dead R_lds -> ~37KB LDS, 4 blocks/CU.
// Downstream (hist, wave scan, rank scatter, int4 writeout) unchanged.

#define NPB       512            // nodes per bucket (9-bit local id)
#define NPB_MASK  511
#define NB_MAX    256
#define TILE      2048           // pairs per lj_bin block
#define SB        8              // accumulation slices

typedef __attribute__((address_space(1))) void g_as1;
typedef __attribute__((address_space(3))) void l_as3;

// Async global->LDS DMA, 16B per lane. LDS dest = wave-uniform base +
// lane*16 (HW rule); global src is per-lane.
__device__ __forceinline__ void async_copy16(void* lds_base, const void* gsrc) {
    __builtin_amdgcn_global_load_lds((g_as1*)gsrc, (l_as3*)lds_base, 16, 0, 0);
}

__device__ __forceinline__ float lj_pair_val(float q, float s6, float s12, float twoeps) {
    const float inv_denom = 1.0f / 262144.0f;   // 1/(100-36)^3, exact pow2
    float inv_r2  = (q > 0.0f) ? (1.0f / q) : 0.0f;
    float inv_r6  = inv_r2 * inv_r2 * inv_r2;
    float inv_r12 = inv_r6 * inv_r6;
    float pair_e  = twoeps * (s12 * inv_r12 - s6 * inv_r6);
    float sw;
    if (q < 36.0f) {
        sw = 1.0f;
    } else if (q < 100.0f) {
        float d = 100.0f - q;
        sw = d * d * (2.0f * q - 8.0f) * inv_denom;
    } else {
        sw = 0.0f;
    }
    return sw * pair_e;
}

// ===== lj_bin: global_load_lds staging, LDS-sourced compute, two-pass rank =====
__global__ __launch_bounds__(256) void lj_bin(
    const float* __restrict__ R, const int* __restrict__ seg,
    const float* __restrict__ sigma_p, const float* __restrict__ eps_p,
    int* __restrict__ bins, int* __restrict__ table,
    float* __restrict__ out, int n_pairs, int n_nodes)
{
    __shared__ int cursor[NB_MAX];                   // per-bucket count
    __shared__ int rankc[NB_MAX];                    // excl-seeded rank counter
    __shared__ int wtot[4];                          // per-wave scan totals
    __shared__ int buckpk[2 * 256];                  // 2KB: 4 bucket bytes/word
    __shared__ __align__(16) float R_lds[TILE * 3];  // 24KB; aliased by ldsdata after pass 1
    __shared__ __align__(16) int seg_lds[TILE];      // 8KB
    int* ldsdata = (int*)R_lds;                      // packed, bucket-grouped (8KB used)

    const int tid = threadIdx.x;
    const int wv = tid >> 6, ln = tid & 63;
    const int tile0  = blockIdx.x * TILE;
    const int nvalid = min(TILE, n_pairs - tile0);

    if (nvalid == TILE) {
        // ---- Async DMA staging: 24 R-insts + 8 seg-insts, 8 per wave,
        // all in flight simultaneously (zero VGPR cost). ----
        const char* Rg = (const char*)(R + (size_t)tile0 * 3);
        #pragma unroll
        for (int r = 0; r < 6; ++r) {
            const int j = wv * 6 + r;                // 0..23, wave-uniform
            async_copy16((char*)R_lds + j * 1024, Rg + j * 1024 + ln * 16);
        }
        const char* Sg = (const char*)(seg + tile0);
        #pragma unroll
        for (int r = 0; r < 2; ++r) {
            const int m = wv * 2 + r;                // 0..7, wave-uniform
            async_copy16((char*)seg_lds + m * 1024, Sg + m * 1024 + ln * 16);
        }
    }

    // Overlap with the DMA: zero this block's chunk of out (replaces the
    // memset dispatch; host guarantees nblocks*64 >= n_nodes on this path)
    // and init the histogram counters.
    {
        const int n = blockIdx.x * 64 + tid;
        if (tid < 64 && n < n_nodes) out[n] = 0.0f;
    }
    cursor[tid] = 0;

    if (nvalid < TILE) {
        // ---- Tail block (last block only): guarded scalar staging ----
        for (int idx = tid; idx < TILE * 3; idx += 256)
            R_lds[idx] = (idx < nvalid * 3) ? R[(size_t)tile0 * 3 + idx] : 0.0f;
        for (int idx = tid; idx < TILE; idx += 256)
            seg_lds[idx] = (idx < nvalid) ? seg[tile0 + idx] : 0;
    }

    asm volatile("s_waitcnt vmcnt(0)" ::: "memory");
    __syncthreads();                               // barrier A

    const float sg = sigma_p[0], ep = eps_p[0];
    const float s2 = sg * sg, s6 = s2 * s2 * s2, s12 = s6 * s6;
    const float twoeps = 2.0f * ep;

    int pint[8];   // packed value|local

    // ---- Pass 1: compute from LDS, no-return histogram, bucket stash ----
    #pragma unroll
    for (int g = 0; g < 2; ++g) {
        const int e0 = g * 1024 + tid * 4;
        const float4 a  = *(const float4*)(R_lds + e0 * 3);
        const float4 b4 = *(const float4*)(R_lds + e0 * 3 + 4);
        const float4 c  = *(const float4*)(R_lds + e0 * 3 + 8);
        const int4  iv  = *(const int4*)(seg_lds + e0);
        const int n0 = iv.x, n1 = iv.y, n2 = iv.z, n3 = iv.w;
        const int b0 = n0 >> 9, b1 = n1 >> 9, b2 = n2 >> 9, b3 = n3 >> 9;
        if (e0 + 0 < nvalid) atomicAdd(&cursor[b0], 1);   // no-rtn ds_add
        if (e0 + 1 < nvalid) atomicAdd(&cursor[b1], 1);
        if (e0 + 2 < nvalid) atomicAdd(&cursor[b2], 1);
        if (e0 + 3 < nvalid) atomicAdd(&cursor[b3], 1);
        buckpk[g * 256 + tid] = b0 | (b1 << 8) | (b2 << 16) | (b3 << 24);
        const float q0 = a.x*a.x + a.y*a.y + a.z*a.z;
        const float q1 = a.w*a.w + b4.x*b4.x + b4.y*b4.y;
        const float q2 = b4.z*b4.z + b4.w*b4.w + c.x*c.x;
        const float q3 = c.y*c.y + c.z*c.z + c.w*c.w;
        pint[g*4+0] = (__float_as_int(lj_pair_val(q0, s6, s12, twoeps)) & ~NPB_MASK) | (n0 & NPB_MASK);
        pint[g*4+1] = (__float_as_int(lj_pair_val(q1, s6, s12, twoeps)) & ~NPB_MASK) | (n1 & NPB_MASK);
        pint[g*4+2] = (__float_as_int(lj_pair_val(q2, s6, s12, twoeps)) & ~NPB_MASK) | (n2 & NPB_MASK);
        pint[g*4+3] = (__float_as_int(lj_pair_val(q3, s6, s12, twoeps)) & ~NPB_MASK) | (n3 & NPB_MASK);
    }

    __syncthreads();                               // barrier B
    // (R_lds/seg_lds dead from here; ldsdata aliases R_lds.)

    // ---- Exclusive scan of the 256 counts: wave-shfl + cross-wave totals ----
    const int cnt = cursor[tid];
    int incl = cnt;
    #pragma unroll
    for (int d = 1; d < 64; d <<= 1) {
        int v = __shfl_up(incl, d);
        if (ln >= d) incl += v;
    }
    if (ln == 63) wtot[wv] = incl;
    __syncthreads();                               // barrier C
    int pre = 0;
    #pragma unroll
    for (int w = 0; w < 4; ++w) pre += (w < wv) ? wtot[w] : 0;
    const int excl = pre + incl - cnt;
    rankc[tid] = excl;                             // seed rank counter with excl
    // Prefix row for this block: start-of-bucket | count<<16 (both <= 2048).
    table[(size_t)blockIdx.x * NB_MAX + tid] = excl | (cnt << 16);
    __syncthreads();                               // barrier D

    // ---- Pass 2: buckets from LDS stash, single rank atomic, LDS scatter ----
    #pragma unroll
    for (int g = 0; g < 2; ++g) {
        const int pk = buckpk[g * 256 + tid];
        #pragma unroll
        for (int k = 0; k < 4; ++k) {
            const int li = g * 1024 + tid * 4 + k;
            if (li < nvalid) {
                const int b = (pk >> (8 * k)) & 255;
                const int pos = atomicAdd(&rankc[b], 1);
                ldsdata[pos] = pint[g * 4 + k];
            }
        }
    }
    __syncthreads();                               // barrier E

    // Unconditional contiguous int4 write of the whole region. Slots beyond
    // the fill point are garbage but never read (accum walks [excl,excl+cnt)).
    int* dst = bins + (size_t)blockIdx.x * TILE;
    #pragma unroll
    for (int g = 0; g < 2; ++g) {
        const int idx = g * 1024 + tid * 4;
        *(int4*)(dst + idx) = *(const int4*)(ldsdata + idx);
    }
}

// ===== lj_accum: one block per (bucket, slice); PER-THREAD regions
// (independent scalar-load streams for MLP), adds straight into out =====
__global__ __launch_bounds__(256) void lj_accum(
    const int* __restrict__ bins, const int* __restrict__ table,
    float* __restrict__ out, int nb, int nblocks, int n_nodes)
{
    const int b = blockIdx.x % nb;
    const int s = blockIdx.x / nb;      // slice index
    const int tid = threadIdx.x;

    __shared__ float acc[NPB];
    for (int l = tid; l < NPB; l += 256) acc[l] = 0.0f;
    __syncthreads();

    // Thread t handles regions rblk = s + SB*(t + 256*iter): independent
    // scalar-load streams, 4-way unrolled -> high memory-level parallelism.
    for (int rblk = s + SB * tid; rblk < nblocks; rblk += SB * 256) {
        const int pe  = table[(size_t)rblk * NB_MAX + b];
        const int cnt = pe >> 16;
        const int* p  = bins + (size_t)rblk * TILE + (pe & 0xFFFF);
        int k = 0;
        for (; k + 3 < cnt; k += 4) {
            const int e0 = p[k], e1 = p[k+1], e2 = p[k+2], e3 = p[k+3];
            atomicAdd(&acc[e0 & NPB_MASK], __int_as_float(e0 & ~NPB_MASK));
            atomicAdd(&acc[e1 & NPB_MASK], __int_as_float(e1 & ~NPB_MASK));
            atomicAdd(&acc[e2 & NPB_MASK], __int_as_float(e2 & ~NPB_MASK));
            atomicAdd(&acc[e3 & NPB_MASK], __int_as_float(e3 & ~NPB_MASK));
        }
        for (; k < cnt; ++k) {
            const int e = p[k];
            atomicAdd(&acc[e & NPB_MASK], __int_as_float(e & ~NPB_MASK));
        }
    }
    __syncthreads();

    const int node0 = b * NPB;
    for (int l = tid; l < NPB; l += 256) {
        const int node = node0 + l;
        if (node < n_nodes) {
            const float v = acc[l];
            if (v != 0.0f) atomicAdd(&out[node], v);
        }
    }
}

// Fallback: direct device-scope atomics (round-1 kernel).
__global__ __launch_bounds__(256) void lj_pair_scatter(
    const float* __restrict__ R, const int* __restrict__ seg,
    const float* __restrict__ sigma_p, const float* __restrict__ eps_p,
    float* __restrict__ out, int n_pairs)
{
    const float sg = sigma_p[0], ep = eps_p[0];
    const float s2 = sg*sg, s6 = s2*s2*s2, s12 = s6*s6;
    const float twoeps = 2.0f * ep;
    const int t = blockIdx.x * blockDim.x + threadIdx.x;
    const int nthreads = gridDim.x * blockDim.x;
    for (int base = t * 4; base < n_pairs; base += nthreads * 4) {
        if (base + 3 < n_pairs) {
            const float4* Rv = (const float4*)(R + (size_t)base * 3);
            float4 a = Rv[0], b = Rv[1], c = Rv[2];
            int4 iv = *(const int4*)(seg + base);
            float r2[4];
            r2[0] = a.x*a.x + a.y*a.y + a.z*a.z;
            r2[1] = a.w*a.w + b.x*b.x + b.y*b.y;
            r2[2] = b.z*b.z + b.w*b.w + c.x*c.x;
            r2[3] = c.y*c.y + c.z*c.z + c.w*c.w;
            const int ii[4] = {iv.x, iv.y, iv.z, iv.w};
            #pragma unroll
            for (int k = 0; k < 4; ++k)
                atomicAdd(&out[ii[k]], lj_pair_val(r2[k], s6, s12, twoeps));
        } else {
            for (int p = base; p < n_pairs; ++p) {
                float x = R[(size_t)p*3], y = R[(size_t)p*3+1], z = R[(size_t)p*3+2];
                atomicAdd(&out[seg[p]], lj_pair_val(x*x+y*y+z*z, s6, s12, twoeps));
            }
        }
    }
}

extern "C" void kernel_launch(void* const* d_in, const int* in_sizes, int n_in,
                              void* d_out, int out_size, void* d_ws, size_t ws_size,
                              hipStream_t stream) {
    // Inputs: 0 R_ij f32[n_pairs,3], 1 i i32[n_pairs], 2 j (unused),
    // 3 Z_i (shape only), 4 pair_mask (all True), 5 node_mask (all True),
    // 6 sigma f32[1], 7 epsilon f32[1]
    const float* R     = (const float*)d_in[0];
    const int*   seg   = (const int*)d_in[1];
    const float* sigma = (const float*)d_in[6];
    const float* eps   = (const float*)d_in[7];
    float* out = (float*)d_out;

    const int n_pairs = in_sizes[1];
    const int n_nodes = out_size;
    const int nb = (n_nodes + NPB - 1) / NPB;
    const int nblocks = (n_pairs + TILE - 1) / TILE;

    const size_t bin_bytes = (size_t)nblocks * TILE * sizeof(int);
    const size_t tab_bytes = (size_t)nblocks * NB_MAX * sizeof(int);
    const size_t need = bin_bytes + tab_bytes;

    if (nb >= 1 && nb <= NB_MAX && nblocks >= 1 && ws_size >= need) {
        int* bins  = (int*)d_ws;
        int* table = (int*)((char*)d_ws + bin_bytes);

        // bin zeroes out's chunks itself when coverage suffices (one fewer
        // dispatch); otherwise fall back to an explicit memset.
        if ((size_t)nblocks * 64 < (size_t)n_nodes)
            hipMemsetAsync(out, 0, (size_t)n_nodes * sizeof(float), stream);

        lj_bin<<<nblocks, 256, 0, stream>>>(R, seg, sigma, eps, bins, table,
                                            out, n_pairs, n_nodes);
        lj_accum<<<nb * SB, 256, 0, stream>>>(bins, table, out, nb, nblocks, n_nodes);
    } else {
        hipMemsetAsync(d_out, 0, (size_t)out_size * sizeof(float), stream);
        const int grid = (n_pairs + 1023) / 1024;
        lj_pair_scatter<<<grid, 256, 0, stream>>>(R, seg, sigma, eps, out, n_pairs);
    }
}